// Round 4
// baseline (407.784 us; speedup 1.0000x reference)
//
#include <hip/hip_runtime.h>

// QReLU: out = x > 0 ? x : -1.99f * x
// fp32 in/out, 268,435,456 elements. Memory-bound streaming op.
//
// R4 change vs R3 (373.8 us, 5.74 TB/s eff = 91% of 6.29 TB/s copy ceiling):
//  UNROLL 8 -> 16: 16 independent nontemporal float4 loads in flight per
//  wave-iteration (16 KB/wave outstanding) to keep the read queue full
//  across the store phase and loop turnaround.

#define BLOCK 256
#define UNROLL 16
#define TILE_F4 (BLOCK * UNROLL)   // 4096 float4s = 64 KB per tile

typedef float f32x4 __attribute__((ext_vector_type(4)));

__device__ __forceinline__ f32x4 qrelu4(f32x4 v) {
    f32x4 r;
    r.x = v.x > 0.0f ? v.x : -1.99f * v.x;
    r.y = v.y > 0.0f ? v.y : -1.99f * v.y;
    r.z = v.z > 0.0f ? v.z : -1.99f * v.z;
    r.w = v.w > 0.0f ? v.w : -1.99f * v.w;
    return r;
}

__global__ void __launch_bounds__(BLOCK) qrelu_f4x16_nt_kernel(
        const f32x4* __restrict__ x, f32x4* __restrict__ out, int ntiles) {
    for (int t = blockIdx.x; t < ntiles; t += gridDim.x) {
        const int base = t * TILE_F4 + threadIdx.x;
        f32x4 v[UNROLL];
#pragma unroll
        for (int u = 0; u < UNROLL; ++u)
            v[u] = __builtin_nontemporal_load(&x[base + u * BLOCK]);
#pragma unroll
        for (int u = 0; u < UNROLL; ++u)
            __builtin_nontemporal_store(qrelu4(v[u]), &out[base + u * BLOCK]);
    }
}

// Scalar tail for any elements beyond the last complete tile.
__global__ void qrelu_tail_kernel(const float* __restrict__ x,
                                  float* __restrict__ out,
                                  int start, int n) {
    int i = start + blockIdx.x * blockDim.x + threadIdx.x;
    if (i < n) {
        float v = x[i];
        out[i] = v > 0.0f ? v : -1.99f * v;
    }
}

extern "C" void kernel_launch(void* const* d_in, const int* in_sizes, int n_in,
                              void* d_out, int out_size, void* d_ws, size_t ws_size,
                              hipStream_t stream) {
    const float* x = (const float*)d_in[0];
    float* out = (float*)d_out;
    const int n = in_sizes[0];

    const int n4 = n / 4;                 // complete float4s
    const int ntiles = n4 / TILE_F4;      // complete tiles
    if (ntiles > 0) {
        int grid = ntiles < 2048 ? ntiles : 2048;
        qrelu_f4x16_nt_kernel<<<grid, BLOCK, 0, stream>>>(
            (const f32x4*)x, (f32x4*)out, ntiles);
    }

    // Tail: elements not covered by complete tiles (none for this shape).
    const int tail_start = ntiles * TILE_F4 * 4;
    const int tail = n - tail_start;
    if (tail > 0) {
        qrelu_tail_kernel<<<(tail + BLOCK - 1) / BLOCK, BLOCK, 0, stream>>>(
            x, out, tail_start, n);
    }
}

// Round 5
// 398.738 us; speedup vs baseline: 1.0227x; 1.0227x over previous
//
#include <hip/hip_runtime.h>

// QReLU: out = x > 0 ? x : -1.99f * x
// fp32 in/out, 268,435,456 elements. Memory-bound streaming op.
//
// History: R2 UNROLL=4 noNT: 403us | R3 UNROLL=8 NT both: 374us (5.74 TB/s)
//          R4 UNROLL=16 NT both: 408us (MLP over-saturation; sweet spot = 8)
// R5 change vs R3: NT on STORES only, plain loads. Isolates whether the NT
// win is write-allocate avoidance (expected) vs load-path bypass.

#define BLOCK 256
#define UNROLL 8
#define TILE_F4 (BLOCK * UNROLL)   // 2048 float4s = 32 KB per tile

typedef float f32x4 __attribute__((ext_vector_type(4)));

__device__ __forceinline__ f32x4 qrelu4(f32x4 v) {
    f32x4 r;
    r.x = v.x > 0.0f ? v.x : -1.99f * v.x;
    r.y = v.y > 0.0f ? v.y : -1.99f * v.y;
    r.z = v.z > 0.0f ? v.z : -1.99f * v.z;
    r.w = v.w > 0.0f ? v.w : -1.99f * v.w;
    return r;
}

__global__ void __launch_bounds__(BLOCK) qrelu_f4x8_ntst_kernel(
        const f32x4* __restrict__ x, f32x4* __restrict__ out, int ntiles) {
    for (int t = blockIdx.x; t < ntiles; t += gridDim.x) {
        const int base = t * TILE_F4 + threadIdx.x;
        f32x4 v[UNROLL];
#pragma unroll
        for (int u = 0; u < UNROLL; ++u)
            v[u] = x[base + u * BLOCK];            // plain (cached) loads
#pragma unroll
        for (int u = 0; u < UNROLL; ++u)
            __builtin_nontemporal_store(qrelu4(v[u]), &out[base + u * BLOCK]);
    }
}

// Scalar tail for any elements beyond the last complete tile.
__global__ void qrelu_tail_kernel(const float* __restrict__ x,
                                  float* __restrict__ out,
                                  int start, int n) {
    int i = start + blockIdx.x * blockDim.x + threadIdx.x;
    if (i < n) {
        float v = x[i];
        out[i] = v > 0.0f ? v : -1.99f * v;
    }
}

extern "C" void kernel_launch(void* const* d_in, const int* in_sizes, int n_in,
                              void* d_out, int out_size, void* d_ws, size_t ws_size,
                              hipStream_t stream) {
    const float* x = (const float*)d_in[0];
    float* out = (float*)d_out;
    const int n = in_sizes[0];

    const int n4 = n / 4;                 // complete float4s
    const int ntiles = n4 / TILE_F4;      // complete tiles
    if (ntiles > 0) {
        int grid = ntiles < 2048 ? ntiles : 2048;
        qrelu_f4x8_ntst_kernel<<<grid, BLOCK, 0, stream>>>(
            (const f32x4*)x, (f32x4*)out, ntiles);
    }

    // Tail: elements not covered by complete tiles (none for this shape).
    const int tail_start = ntiles * TILE_F4 * 4;
    const int tail = n - tail_start;
    if (tail > 0) {
        qrelu_tail_kernel<<<(tail + BLOCK - 1) / BLOCK, BLOCK, 0, stream>>>(
            x, out, tail_start, n);
    }
}

// Round 6
// 377.107 us; speedup vs baseline: 1.0813x; 1.0574x over previous
//
#include <hip/hip_runtime.h>

// QReLU: out = x > 0 ? x : -1.99f * x
// fp32 in/out, 268,435,456 elements. Memory-bound streaming op.
//
// History: R2 u4/noNT 403 | R3 u8/NT-both 374 (5.74 TB/s, 91% copy ceiling)
//          R4 u16/NT-both 408 (MLP oversaturation) | R5 u8/NT-store-only 399
// R6 change vs R3: 2-stage ping-pong software pipeline — issue tile t+1's
// 8 NT loads BEFORE storing tile t (alternating reg banks, no reg copies),
// so the read queue never drains at loop turnaround.

#define BLOCK 256
#define UNROLL 8
#define TILE_F4 (BLOCK * UNROLL)   // 2048 float4s = 32 KB per tile

typedef float f32x4 __attribute__((ext_vector_type(4)));

__device__ __forceinline__ f32x4 qrelu4(f32x4 v) {
    f32x4 r;
    r.x = v.x > 0.0f ? v.x : -1.99f * v.x;
    r.y = v.y > 0.0f ? v.y : -1.99f * v.y;
    r.z = v.z > 0.0f ? v.z : -1.99f * v.z;
    r.w = v.w > 0.0f ? v.w : -1.99f * v.w;
    return r;
}

#define LOAD_TILE(dst, t)                                                   \
    {                                                                       \
        const int _b = (t) * TILE_F4 + (int)threadIdx.x;                    \
        _Pragma("unroll")                                                   \
        for (int u = 0; u < UNROLL; ++u)                                    \
            dst[u] = __builtin_nontemporal_load(&x[_b + u * BLOCK]);        \
    }

#define STORE_TILE(src, t)                                                  \
    {                                                                       \
        const int _b = (t) * TILE_F4 + (int)threadIdx.x;                    \
        _Pragma("unroll")                                                   \
        for (int u = 0; u < UNROLL; ++u)                                    \
            __builtin_nontemporal_store(qrelu4(src[u]), &out[_b + u * BLOCK]); \
    }

__global__ void __launch_bounds__(BLOCK) qrelu_pipe_kernel(
        const f32x4* __restrict__ x, f32x4* __restrict__ out, int ntiles) {
    const int gstride = gridDim.x;
    int t = blockIdx.x;           // guaranteed < ntiles (grid <= ntiles)
    f32x4 va[UNROLL], vb[UNROLL];
    LOAD_TILE(va, t);
    for (;;) {
        const int t1 = t + gstride;
        if (t1 < ntiles) LOAD_TILE(vb, t1);   // next-tile loads in flight...
        STORE_TILE(va, t);                    // ...before this tile's stores
        if (t1 >= ntiles) return;
        const int t2 = t1 + gstride;
        if (t2 < ntiles) LOAD_TILE(va, t2);
        STORE_TILE(vb, t1);
        if (t2 >= ntiles) return;
        t = t2;
    }
}

// Scalar tail for any elements beyond the last complete tile.
__global__ void qrelu_tail_kernel(const float* __restrict__ x,
                                  float* __restrict__ out,
                                  int start, int n) {
    int i = start + blockIdx.x * blockDim.x + threadIdx.x;
    if (i < n) {
        float v = x[i];
        out[i] = v > 0.0f ? v : -1.99f * v;
    }
}

extern "C" void kernel_launch(void* const* d_in, const int* in_sizes, int n_in,
                              void* d_out, int out_size, void* d_ws, size_t ws_size,
                              hipStream_t stream) {
    const float* x = (const float*)d_in[0];
    float* out = (float*)d_out;
    const int n = in_sizes[0];

    const int n4 = n / 4;                 // complete float4s
    const int ntiles = n4 / TILE_F4;      // complete tiles
    if (ntiles > 0) {
        int grid = ntiles < 2048 ? ntiles : 2048;
        qrelu_pipe_kernel<<<grid, BLOCK, 0, stream>>>(
            (const f32x4*)x, (f32x4*)out, ntiles);
    }

    // Tail: elements not covered by complete tiles (none for this shape).
    const int tail_start = ntiles * TILE_F4 * 4;
    const int tail = n - tail_start;
    if (tail > 0) {
        qrelu_tail_kernel<<<(tail + BLOCK - 1) / BLOCK, BLOCK, 0, stream>>>(
            x, out, tail_start, n);
    }
}